// Round 5
// baseline (258.438 us; speedup 1.0000x reference)
//
#include <hip/hip_runtime.h>

#define HW (1024 * 1024)
#define PLANE 8388608   // C * WS * WS = 512 * 16384

typedef _Float16 half4 __attribute__((ext_vector_type(4)));
typedef _Float16 half8 __attribute__((ext_vector_type(8)));
typedef float floatx4 __attribute__((ext_vector_type(4)));

// Single fused kernel, grid (8, 512, 9), 512 threads:
//  z in [0,8): MLP role. d=blockIdx.x is the image band (128 rows, pinned to
//    XCD d via linear%8 round-robin). Window w=blockIdx.y, row-group g=z
//    (16 window rows). Block processes rows of group g lying in band d:
//    phase 1 computes P = W1^T xs for those pixels into LDS (fp16),
//    phase 2 runs h1=relu(P-q); h2=relu(W2^T h1+b2) via MFMA; sigmoid; store.
//  z == 8: iidd role — writes the 3 index planes (4096 blocks).
__global__ __launch_bounds__(512) void instanseg_fused(
    const float* __restrict__ x,      // (6, 1024, 1024)
    const float* __restrict__ sigma,  // (1, 1024, 1024)
    const float* __restrict__ c,      // (512, 6)
    const float* __restrict__ W1,     // (7, 16)
    const float* __restrict__ b1,     // (16)
    const float* __restrict__ W2,     // (16, 16)
    const float* __restrict__ b2,     // (16)
    const float* __restrict__ W3,     // (16, 1)
    const float* __restrict__ b3,     // (1)
    const int*   __restrict__ cent,   // (512, 2)
    float* __restrict__ out)
{
    __shared__ _Float16 PL[16 * 128 * 16];   // 64 KB: up to 16 rows x 128 px x 16 ch

    if (blockIdx.z == 8) {
        // ---- iidd role: 4096 blocks, each writes 1/8 of one window's planes
        const int id  = blockIdx.x + 8 * blockIdx.y;
        const int w   = id >> 3;
        const int oct = id & 7;
        const int cy0 = min(max(cent[2 * w], 64), 960) - 64;
        const int cx0 = min(max(cent[2 * w + 1], 64), 960) - 64;
        const int p   = oct * 2048 + threadIdx.x * 4;
        const int n   = w * 16384 + p;
        const float iw  = (float)w;
        const float row = (float)(cy0 + (p >> 7));
        const float c0  = (float)(cx0 + (p & 127));
        float4 iv = {iw, iw, iw, iw};
        float4 rv = {row, row, row, row};
        float4 cv = {c0, c0 + 1.0f, c0 + 2.0f, c0 + 3.0f};
        *(float4*)(out + PLANE + n)     = iv;
        *(float4*)(out + 2 * PLANE + n) = rv;
        *(float4*)(out + 3 * PLANE + n) = cv;
        return;
    }

    // ---- MLP role
    const int d = blockIdx.x;          // band / XCD
    const int w = blockIdx.y;          // window
    const int g = blockIdx.z;          // 16-row group within window

    const int cy0 = min(max(cent[2 * w], 64), 960) - 64;
    const int cx0 = min(max(cent[2 * w + 1], 64), 960) - 64;

    const int gr0 = cy0 + 16 * g;                  // group's first global row
    const int r0  = max(gr0, 128 * d);
    const int r1  = min(gr0 + 16, 128 * d + 128);
    if (r0 >= r1) return;                          // group not in this band
    const int nrows = r1 - r0;
    const int npx   = nrows * 128;

    // phase 1: P into LDS
    for (int p = threadIdx.x; p < npx; p += 512) {
        const int src = (r0 + (p >> 7)) * 1024 + cx0 + (p & 127);
        float gch[7];
#pragma unroll
        for (int e = 0; e < 6; ++e) gch[e] = x[e * HW + src];
        gch[6] = sigma[src];

        half8 lo, hi;
#pragma unroll
        for (int j = 0; j < 16; ++j) {
            float a = 0.0f;
#pragma unroll
            for (int e = 0; e < 7; ++e)
                a = fmaf(gch[e], W1[e * 16 + j], a);
            if (j < 8) lo[j] = (_Float16)a; else hi[j - 8] = (_Float16)a;
        }
        *(half8*)(PL + p * 16)     = lo;
        *(half8*)(PL + p * 16 + 8) = hi;
    }
    __syncthreads();

    // phase 2: MFMA over LDS
    const int lane = threadIdx.x & 63;
    const int wave = threadIdx.x >> 6;
    const int quad = lane >> 4;
    const int sub  = lane & 15;

    half4 a2, qh;
    float w3f[4], bb2[4];
#pragma unroll
    for (int i = 0; i < 4; ++i) {
        const int k = 4 * quad + i;
        a2[i]  = (_Float16)W2[k * 16 + sub];
        w3f[i] = W3[k];
        bb2[i] = b2[k];
        float qv = -b1[k];
#pragma unroll
        for (int e = 0; e < 6; ++e)
            qv = fmaf(W1[e * 16 + k], c[w * 6 + e], qv);
        qh[i] = (_Float16)qv;
    }
    const float b3v = b3[0];
    const floatx4 zero = {0.0f, 0.0f, 0.0f, 0.0f};

    const int wrbase = r0 - cy0;          // window-row of local pixel 0
    const int n_iter = nrows * 2;         // 64-px iterations

    for (int it = wave; it < n_iter; it += 8) {
        const int p0 = it * 64;
        float logit[4];
#pragma unroll
        for (int ch = 0; ch < 4; ++ch) {
            half4 v = *(const half4*)(PL + (p0 + ch * 16 + sub) * 16 + quad * 4);
            half4 h = v - qh;
#pragma unroll
            for (int i = 0; i < 4; ++i)
                h[i] = h[i] > (_Float16)0.0f ? h[i] : (_Float16)0.0f;

            floatx4 c2 = __builtin_amdgcn_mfma_f32_16x16x16f16(a2, h, zero, 0, 0, 0);

            float part = 0.0f;
#pragma unroll
            for (int i = 0; i < 4; ++i)
                part = fmaf(w3f[i], fmaxf(c2[i] + bb2[i], 0.0f), part);
            part += __shfl_xor(part, 16, 64);
            part += __shfl_xor(part, 32, 64);
            logit[ch] = part;
        }

        const float l01 = (quad & 1) ? logit[1] : logit[0];
        const float l23 = (quad & 1) ? logit[3] : logit[2];
        const float lg  = (quad & 2) ? l23 : l01;
        const float prob = __builtin_amdgcn_rcpf(1.0f + __expf(-(lg + b3v)));

        const int pl = p0 + lane;
        out[w * 16384 + (wrbase + (pl >> 7)) * 128 + (pl & 127)] = prob;
    }
}

extern "C" void kernel_launch(void* const* d_in, const int* in_sizes, int n_in,
                              void* d_out, int out_size, void* d_ws, size_t ws_size,
                              hipStream_t stream) {
    const float* x     = (const float*)d_in[0];
    const float* sigma = (const float*)d_in[1];
    const float* c     = (const float*)d_in[2];
    const float* W1    = (const float*)d_in[3];
    const float* b1    = (const float*)d_in[4];
    const float* W2    = (const float*)d_in[5];
    const float* b2    = (const float*)d_in[6];
    const float* W3    = (const float*)d_in[7];
    const float* b3    = (const float*)d_in[8];
    const int*   cent  = (const int*)d_in[9];
    float* out = (float*)d_out;

    instanseg_fused<<<dim3(8, 512, 9), dim3(512), 0, stream>>>(
        x, sigma, c, W1, b1, W2, b2, W3, b3, cent, out);
}

// Round 7
// 217.546 us; speedup vs baseline: 1.1880x; 1.1880x over previous
//
#include <hip/hip_runtime.h>

#define HW (1024 * 1024)
#define PLANE 8388608   // C * WS * WS = 512 * 16384

typedef _Float16 half4 __attribute__((ext_vector_type(4)));
typedef _Float16 half8 __attribute__((ext_vector_type(8)));
typedef float floatx4 __attribute__((ext_vector_type(4)));

// d_ws layout: int counts[8] at offset 0; int lists[8][1024] at offset 16 ints.
// P (fp16, px-major, 32 MB) at byte offset 64 KB.

// K0: bucket the 4096 (window, 16-row-group) pairs by image band (128 rows).
__global__ __launch_bounds__(512) void build_worklist(
    const int* __restrict__ cent, int* __restrict__ ws)
{
    __shared__ int cnt[8];
    if (threadIdx.x < 8) cnt[threadIdx.x] = 0;
    __syncthreads();
    for (int t = threadIdx.x; t < 4096; t += 512) {
        const int w = t >> 3, g = t & 7;
        const int cy0 = min(max(cent[2 * w], 64), 960) - 64;
        const int mid = cy0 + 16 * g + 8;        // group midpoint row
        const int d = mid >> 7;                  // band 0..7
        const int slot = atomicAdd(&cnt[d], 1);
        ws[16 + d * 1024 + slot] = t;
    }
    __syncthreads();
    if (threadIdx.x < 8) ws[threadIdx.x] = cnt[threadIdx.x];
}

// K1: P[src][j] = sum_e W1[e][j]*xs[e][src], band-pinned: blockIdx.x = band
// -> XCD (linear%8), so band d's 4 MB of P is written through XCD d's L2.
__global__ __launch_bounds__(256) void prep(
    const float* __restrict__ x,      // (6, 1024, 1024)
    const float* __restrict__ sigma,  // (1, 1024, 1024)
    const float* __restrict__ W1,     // (7, 16)
    _Float16* __restrict__ P)         // (1024*1024, 16)
{
    const int px = blockIdx.x * 131072 + blockIdx.y * 256 + threadIdx.x;
    float g[7];
#pragma unroll
    for (int e = 0; e < 6; ++e) g[e] = x[e * HW + px];
    g[6] = sigma[px];

    half8 lo, hi;
#pragma unroll
    for (int j = 0; j < 16; ++j) {
        float a = 0.0f;
#pragma unroll
        for (int e = 0; e < 7; ++e)
            a = fmaf(g[e], W1[e * 16 + j], a);
        if (j < 8) lo[j] = (_Float16)a; else hi[j - 8] = (_Float16)a;
    }
    *(half8*)(P + (size_t)px * 16)     = lo;
    *(half8*)(P + (size_t)px * 16 + 8) = hi;
}

// K2: grid (8, 1152). blockIdx.x = band d (-> XCD d).
//   by <  128 : iidd role — nontemporal writes of the 3 index planes.
//   by >= 128 : MLP role — i-th worklist entry of band d; P reads hit XCD-d L2.
__global__ __launch_bounds__(256) void mlp(
    const _Float16* __restrict__ P,
    const int* __restrict__ ws,       // counts + lists
    const float* __restrict__ c,      // (512, 6)
    const float* __restrict__ W1,     // (7, 16)
    const float* __restrict__ b1,     // (16)
    const float* __restrict__ W2,     // (16, 16)
    const float* __restrict__ b2,     // (16)
    const float* __restrict__ W3,     // (16, 1)
    const float* __restrict__ b3,     // (1)
    const int*   __restrict__ cent,   // (512, 2)
    float* __restrict__ out)
{
    const int d = blockIdx.x;

    if (blockIdx.y < 128) {
        // ---- iidd role: 1024 blocks, each writes half a window's 3 planes
        const int j    = d * 128 + blockIdx.y;
        const int w    = j >> 1;
        const int half = j & 1;
        const int cy0 = min(max(cent[2 * w], 64), 960) - 64;
        const int cx0 = min(max(cent[2 * w + 1], 64), 960) - 64;
        const float iw = (float)w;
#pragma unroll
        for (int pass = 0; pass < 8; ++pass) {
            const int p = half * 8192 + pass * 1024 + threadIdx.x * 4;
            const int n = w * 16384 + p;
            const float row = (float)(cy0 + (p >> 7));
            const float c0  = (float)(cx0 + (p & 127));
            floatx4 iv = {iw, iw, iw, iw};
            floatx4 rv = {row, row, row, row};
            floatx4 cv = {c0, c0 + 1.0f, c0 + 2.0f, c0 + 3.0f};
            __builtin_nontemporal_store(iv, (floatx4*)(out + PLANE + n));
            __builtin_nontemporal_store(rv, (floatx4*)(out + 2 * PLANE + n));
            __builtin_nontemporal_store(cv, (floatx4*)(out + 3 * PLANE + n));
        }
        return;
    }

    const int i = blockIdx.y - 128;
    if (i >= ws[d]) return;                       // band's worklist exhausted
    const int t = ws[16 + d * 1024 + i];
    const int w = t >> 3, g = t & 7;

    const int cy0 = min(max(cent[2 * w], 64), 960) - 64;
    const int cx0 = min(max(cent[2 * w + 1], 64), 960) - 64;

    const int lane = threadIdx.x & 63;
    const int wave = threadIdx.x >> 6;
    const int quad = lane >> 4;
    const int sub  = lane & 15;

    // A-fragment: A[m=sub][k=4*quad+i] = W2[k][m];  q = W1_x^T c - b1 (fp16)
    half4 a2, qh;
    float w3f[4], bb2[4];
#pragma unroll
    for (int ii = 0; ii < 4; ++ii) {
        const int k = 4 * quad + ii;
        a2[ii]  = (_Float16)W2[k * 16 + sub];
        w3f[ii] = W3[k];
        bb2[ii] = b2[k];
        float qv = -b1[k];
#pragma unroll
        for (int e = 0; e < 6; ++e)
            qv = fmaf(W1[e * 16 + k], c[w * 6 + e], qv);
        qh[ii] = (_Float16)qv;
    }
    const float b3v = b3[0];
    const floatx4 zero = {0.0f, 0.0f, 0.0f, 0.0f};

    // this block: window rows 16g..16g+15 = window-pixels [g*2048, g*2048+2048)
#pragma unroll 2
    for (int it = wave; it < 32; it += 4) {
        const int start = g * 2048 + it * 64;     // multiple of 64, one row
        const int srcbase = (cy0 + (start >> 7)) * 1024 + cx0 + (start & 127);
        const _Float16* pb = P + (size_t)(srcbase + sub) * 16 + quad * 4;

        float logit[4];
#pragma unroll
        for (int ch = 0; ch < 4; ++ch) {
            half4 v = *(const half4*)(pb + ch * 256);   // +16 px = 512 B imm
            half4 h = v - qh;
#pragma unroll
            for (int ii = 0; ii < 4; ++ii)
                h[ii] = h[ii] > (_Float16)0.0f ? h[ii] : (_Float16)0.0f;

            floatx4 c2 = __builtin_amdgcn_mfma_f32_16x16x16f16(a2, h, zero, 0, 0, 0);

            float part = 0.0f;
#pragma unroll
            for (int ii = 0; ii < 4; ++ii)
                part = fmaf(w3f[ii], fmaxf(c2[ii] + bb2[ii], 0.0f), part);
            part += __shfl_xor(part, 16, 64);
            part += __shfl_xor(part, 32, 64);
            logit[ch] = part;
        }

        const float l01 = (quad & 1) ? logit[1] : logit[0];
        const float l23 = (quad & 1) ? logit[3] : logit[2];
        const float lg  = (quad & 2) ? l23 : l01;
        const float prob = __builtin_amdgcn_rcpf(1.0f + __expf(-(lg + b3v)));

        __builtin_nontemporal_store(prob, out + w * 16384 + start + lane);
    }
}

extern "C" void kernel_launch(void* const* d_in, const int* in_sizes, int n_in,
                              void* d_out, int out_size, void* d_ws, size_t ws_size,
                              hipStream_t stream) {
    const float* x     = (const float*)d_in[0];
    const float* sigma = (const float*)d_in[1];
    const float* c     = (const float*)d_in[2];
    const float* W1    = (const float*)d_in[3];
    const float* b1    = (const float*)d_in[4];
    const float* W2    = (const float*)d_in[5];
    const float* b2    = (const float*)d_in[6];
    const float* W3    = (const float*)d_in[7];
    const float* b3    = (const float*)d_in[8];
    const int*   cent  = (const int*)d_in[9];
    float* out = (float*)d_out;

    int* wsl    = (int*)d_ws;                          // counts + worklists
    _Float16* P = (_Float16*)((char*)d_ws + 65536);    // 32 MB fp16

    build_worklist<<<dim3(1), dim3(512), 0, stream>>>(cent, wsl);
    prep<<<dim3(8, 512), dim3(256), 0, stream>>>(x, sigma, W1, P);
    mlp<<<dim3(8, 1152), dim3(256), 0, stream>>>(
        P, wsl, c, W1, b1, W2, b2, W3, b3, cent, out);
}